// Round 13
// baseline (5175.386 us; speedup 1.0000x reference)
//
#include <hip/hip_runtime.h>
#include <stdint.h>

#define BDIM 256
#define SEQL 128
#define IND 512
#define HID 512
#define KDIM 1024 // IND + HID

typedef __bf16 bf16x8 __attribute__((ext_vector_type(8)));
typedef float floatx4 __attribute__((ext_vector_type(4)));
typedef _Float16 f16x8 __attribute__((ext_vector_type(8)));

__device__ __forceinline__ float sigm(float x) { return 1.0f / (1.0f + __expf(-x)); }

__device__ __forceinline__ ushort f2bf(float v) {
  uint32_t x = __builtin_bit_cast(uint32_t, v);
  x += 0x7fffu + ((x >> 16) & 1u);
  return (ushort)(x >> 16);
}
__device__ __forceinline__ float bf2f(ushort u) {
  return __builtin_bit_cast(float, ((uint32_t)u) << 16);
}

// ---- one-time: W -> bf16 hi/lo in [4H][IN|HID] row-major; combined bias ----
__global__ __launch_bounds__(256) void k_wconv(
    const float* __restrict__ W_ih, const float* __restrict__ W_hh,
    const float* __restrict__ b_ih, const float* __restrict__ b_hh,
    ushort* __restrict__ Whi, ushort* __restrict__ Wlo, float* __restrict__ bias) {
  int row = blockIdx.x;
  if (threadIdx.x == 0) bias[row] = b_ih[row] + b_hh[row];
  for (int k = threadIdx.x; k < KDIM; k += 256) {
    float w = (k < IND) ? W_ih[(size_t)row * IND + k] : W_hh[(size_t)row * HID + (k - IND)];
    ushort hi = f2bf(w);
    Whi[(size_t)row * KDIM + k] = hi;
    Wlo[(size_t)row * KDIM + k] = f2bf(w - bf2f(hi));
  }
}

// ---- one-time: x -> fp16 (R12-proven: halves the BW-bound xi stream) ----
__global__ __launch_bounds__(256) void k_xconv(const float* __restrict__ x,
                                               _Float16* __restrict__ xh) {
  size_t i = ((size_t)blockIdx.x * 256 + threadIdx.x) * 8;
  float4 v0 = *(const float4*)(x + i);
  float4 v1 = *(const float4*)(x + i + 4);
  f16x8 o;
  o[0] = (_Float16)v0.x; o[1] = (_Float16)v0.y; o[2] = (_Float16)v0.z; o[3] = (_Float16)v0.w;
  o[4] = (_Float16)v1.x; o[5] = (_Float16)v1.y; o[6] = (_Float16)v1.z; o[7] = (_Float16)v1.w;
  *(f16x8*)(xh + i) = o;
}

// ---- init: h0,c0 from the zero-input zero-state cell (gates = bias) ----
__global__ void k_init(const float* __restrict__ b_ih, const float* __restrict__ b_hh,
                       float* __restrict__ c, ushort* __restrict__ Ahi, ushort* __restrict__ Alo) {
  int b = blockIdx.x;
  for (int j = threadIdx.x; j < HID; j += blockDim.x) {
    float bi = b_ih[j] + b_hh[j];
    float bg = b_ih[2 * HID + j] + b_hh[2 * HID + j];
    float bo = b_ih[3 * HID + j] + b_hh[3 * HID + j];
    float c0 = sigm(bi) * tanhf(bg);
    float h0 = sigm(bo) * tanhf(c0);
    c[b * HID + j] = c0;
    ushort hi = f2bf(h0);
    Ahi[(size_t)b * KDIM + IND + j] = hi;
    Alo[(size_t)b * KDIM + IND + j] = f2bf(h0 - bf2f(hi));
  }
}

struct AttnS { float sc[HID]; float sl[SEQL]; float sxi[4][HID]; };
struct GateS {
  ushort sA[2][2][16][72];       // [buf][hi/lo][batch][k]   9.0 KB
  ushort sW[2][2][2][64][72];    // [buf][tile][hi/lo][row][k] 72 KB
  float  sR[2][4][16][16];       // [tile][gate][j][b]        8 KB
};
union SU { AttnS a; GateS g; };  // 89 KB -> exactly 1 block/CU

// 16-way group sync (group = batch-tile bt; only xi crosses it).
// Monotonic counter, release-add / relaxed-spin / single acquire (R3-proven
// ordering). Never reset -> no ABA; max value 16*128 = 2048.
__device__ __forceinline__ void gsync(unsigned* cnt, unsigned target) {
  __syncthreads();
  if (threadIdx.x == 0) {
    __hip_atomic_fetch_add(cnt, 1u, __ATOMIC_RELEASE, __HIP_MEMORY_SCOPE_AGENT);
    while (__hip_atomic_load(cnt, __ATOMIC_RELAXED, __HIP_MEMORY_SCOPE_AGENT) < target)
      __builtin_amdgcn_s_sleep(4);
    (void)__hip_atomic_load(cnt, __ATOMIC_ACQUIRE, __HIP_MEMORY_SCOPE_AGENT);
  }
  __syncthreads();
}

// merged-gates staging: A staged once, W for BOTH j-tiles (shared batch tile)
#define MLOAD(R, KO) do { \
  R##a   = *(const uint4*)(gA + (KO)); \
  R##w00 = *(const uint4*)(gW0hi + (KO)); R##w01 = *(const uint4*)(gW0hi + (KO) + 8); \
  R##w02 = *(const uint4*)(gW0lo + (KO)); R##w03 = *(const uint4*)(gW0lo + (KO) + 8); \
  R##w10 = *(const uint4*)(gW1hi + (KO)); R##w11 = *(const uint4*)(gW1hi + (KO) + 8); \
  R##w12 = *(const uint4*)(gW1lo + (KO)); R##w13 = *(const uint4*)(gW1lo + (KO) + 8); } while (0)
#define MSTORE(BUF, R) do { \
  *(uint4*)&su.g.sA[BUF][sthalf][ar][ac] = R##a; \
  *(uint4*)&su.g.sW[BUF][0][0][wr][wc] = R##w00; *(uint4*)&su.g.sW[BUF][0][0][wr][wc + 8] = R##w01; \
  *(uint4*)&su.g.sW[BUF][0][1][wr][wc] = R##w02; *(uint4*)&su.g.sW[BUF][0][1][wr][wc + 8] = R##w03; \
  *(uint4*)&su.g.sW[BUF][1][0][wr][wc] = R##w10; *(uint4*)&su.g.sW[BUF][1][0][wr][wc + 8] = R##w11; \
  *(uint4*)&su.g.sW[BUF][1][1][wr][wc] = R##w12; *(uint4*)&su.g.sW[BUF][1][1][wr][wc + 8] = R##w13; } while (0)
#define MCOMPUTE(BUF) do { \
  _Pragma("unroll") for (int ks = 0; ks < 2; ++ks) { \
    int kb = ks * 32 + koff; \
    bf16x8 ah = *(const bf16x8*)(&su.g.sA[BUF][0][ml][kb]); \
    bf16x8 al = *(const bf16x8*)(&su.g.sA[BUF][1][ml][kb]); \
    bf16x8 wh0 = *(const bf16x8*)(&su.g.sW[BUF][0][0][g * 16 + ml][kb]); \
    bf16x8 wl0 = *(const bf16x8*)(&su.g.sW[BUF][0][1][g * 16 + ml][kb]); \
    bf16x8 wh1 = *(const bf16x8*)(&su.g.sW[BUF][1][0][g * 16 + ml][kb]); \
    bf16x8 wl1 = *(const bf16x8*)(&su.g.sW[BUF][1][1][g * 16 + ml][kb]); \
    acc0A = __builtin_amdgcn_mfma_f32_16x16x32_bf16(ah, wh0, acc0A, 0, 0, 0); \
    acc1A = __builtin_amdgcn_mfma_f32_16x16x32_bf16(ah, wh1, acc1A, 0, 0, 0); \
    acc0B = __builtin_amdgcn_mfma_f32_16x16x32_bf16(ah, wl0, acc0B, 0, 0, 0); \
    acc0B = __builtin_amdgcn_mfma_f32_16x16x32_bf16(al, wh0, acc0B, 0, 0, 0); \
    acc1B = __builtin_amdgcn_mfma_f32_16x16x32_bf16(ah, wl1, acc1B, 0, 0, 0); \
    acc1B = __builtin_amdgcn_mfma_f32_16x16x32_bf16(al, wh1, acc1B, 0, 0, 0); } } while (0)

// ---- one step fused: attn(my batch) -> 16-way group sync -> gates(2 j-tiles)
// Group bt = 16 blocks (2 per XCD); cross-group data fully disjoint.
__global__ __launch_bounds__(256) void k_step(
    float* __restrict__ c, const float* __restrict__ Wa,
    const float* __restrict__ ba, const _Float16* __restrict__ xh,
    const ushort* __restrict__ Whi, const ushort* __restrict__ Wlo,
    const float* __restrict__ bias,
    const ushort* __restrict__ Rhi, const ushort* __restrict__ Rlo,
    ushort* __restrict__ Dhi, ushort* __restrict__ Dlo,
    float* __restrict__ out, unsigned* __restrict__ bar, int t) {
  __shared__ __align__(16) SU su;
  int blk = blockIdx.x, tid = threadIdx.x;
  int lane = tid & 63, wave = tid >> 6;
  // decode: XCD n owns j-tiles 4n..4n+3 (W ~1MB L2-resident, R9 map)
  int n = blk & 7, s = blk >> 3;
  int bt = s & 15, psel = s >> 4;
  int b0 = bt * 16;
  int myb = b0 + 2 * n + psel;        // this block's attn batch
  int j0a = (4 * n + 2 * psel) * 16;  // gates tile pair: j0a, j0a+16
  int j0b = j0a + 16;

  // ================= ATTN (R12-proven body, batch = myb) =================
  {
    su.a.sc[tid] = c[myb * HID + tid];
    su.a.sc[tid + 256] = c[myb * HID + tid + 256];
    __syncthreads();
    float4 c0 = *(const float4*)(&su.a.sc[lane * 4]);
    float4 c1 = *(const float4*)(&su.a.sc[lane * 4 + 256]);
#pragma unroll 4
    for (int si = 0; si < 32; ++si) {
      int ss = wave * 32 + si;
      const float4* wr4 = (const float4*)(Wa + (size_t)ss * HID);
      float4 w0 = wr4[lane];
      float4 w1 = wr4[lane + 64];
      float acc = c0.x * w0.x + c0.y * w0.y + c0.z * w0.z + c0.w * w0.w
                + c1.x * w1.x + c1.y * w1.y + c1.z * w1.z + c1.w * w1.w;
#pragma unroll
      for (int off = 32; off > 0; off >>= 1) acc += __shfl_down(acc, off);
      if (lane == 0) su.a.sl[ss] = acc + ba[ss];
    }
    __syncthreads();
    if (tid < 64) {
      float v0 = su.a.sl[tid], v1 = su.a.sl[tid + 64];
      float m = fmaxf(v0, v1);
#pragma unroll
      for (int off = 32; off > 0; off >>= 1) m = fmaxf(m, __shfl_xor(m, off));
      float e0 = __expf(v0 - m), e1 = __expf(v1 - m);
      float s2 = e0 + e1;
#pragma unroll
      for (int off = 32; off > 0; off >>= 1) s2 += __shfl_xor(s2, off);
      float inv = 1.f / s2;
      su.a.sl[tid] = e0 * inv; su.a.sl[tid + 64] = e1 * inv;
    }
    __syncthreads();
    int cix = tid & 63, qp = tid >> 6;
    const _Float16* xrow = xh + (size_t)myb * SEQL * IND + (size_t)qp * 32 * IND + 8 * cix;
    float a0 = 0.f, a1 = 0.f, a2 = 0.f, a3 = 0.f, a4 = 0.f, a5 = 0.f, a6 = 0.f, a7 = 0.f;
#pragma unroll 8
    for (int ss = 0; ss < 32; ++ss) {
      float w = su.a.sl[qp * 32 + ss];
      f16x8 v = *(const f16x8*)(xrow + (size_t)ss * IND);
      a0 += w * (float)v[0]; a1 += w * (float)v[1];
      a2 += w * (float)v[2]; a3 += w * (float)v[3];
      a4 += w * (float)v[4]; a5 += w * (float)v[5];
      a6 += w * (float)v[6]; a7 += w * (float)v[7];
    }
    *(float4*)(&su.a.sxi[qp][8 * cix])     = (float4){a0, a1, a2, a3};
    *(float4*)(&su.a.sxi[qp][8 * cix + 4]) = (float4){a4, a5, a6, a7};
    __syncthreads();
    float rx = su.a.sxi[0][2 * tid] + su.a.sxi[1][2 * tid] + su.a.sxi[2][2 * tid] + su.a.sxi[3][2 * tid];
    float ry = su.a.sxi[0][2 * tid + 1] + su.a.sxi[1][2 * tid + 1] + su.a.sxi[2][2 * tid + 1] + su.a.sxi[3][2 * tid + 1];
    ushort hx = f2bf(rx), hy = f2bf(ry);
    uint hp = (uint)hx | ((uint)hy << 16);
    uint lp = (uint)f2bf(rx - bf2f(hx)) | ((uint)f2bf(ry - bf2f(hy)) << 16);
    *(uint*)(const_cast<ushort*>(Rhi) + (size_t)myb * KDIM + 2 * tid) = hp;
    *(uint*)(const_cast<ushort*>(Rlo) + (size_t)myb * KDIM + 2 * tid) = lp;
  }

  // ================= group sync: xi of all 16 group batches ready =========
  gsync(bar + bt * 16, 16u * (unsigned)(t + 1));

  // ================= merged GATES: 2 j-tiles, shared A-stage ==============
  {
    int sthalf = tid >> 7;
    int ar = (tid & 127) >> 3, ac = (tid & 7) * 8;
    const ushort* gA = (sthalf ? Rlo : Rhi) + (size_t)(b0 + ar) * KDIM + ac;
    int wr = tid >> 2, wc = (tid & 3) * 16;
    int wrow0 = (wr >> 4) * HID + j0a + (wr & 15);
    const ushort* gW0hi = Whi + (size_t)wrow0 * KDIM + wc;
    const ushort* gW0lo = Wlo + (size_t)wrow0 * KDIM + wc;
    const ushort* gW1hi = Whi + (size_t)(wrow0 + 16) * KDIM + wc;
    const ushort* gW1lo = Wlo + (size_t)(wrow0 + 16) * KDIM + wc;

    floatx4 acc0A = {0.f, 0.f, 0.f, 0.f}, acc0B = {0.f, 0.f, 0.f, 0.f};
    floatx4 acc1A = {0.f, 0.f, 0.f, 0.f}, acc1B = {0.f, 0.f, 0.f, 0.f};
    int g = tid >> 6, ml = lane & 15, koff = (lane >> 4) * 8;

    uint4 Aa, Aw00, Aw01, Aw02, Aw03, Aw10, Aw11, Aw12, Aw13;
    uint4 Ba, Bw00, Bw01, Bw02, Bw03, Bw10, Bw11, Bw12, Bw13;

    MLOAD(A, 0);
    MLOAD(B, 64);
    MSTORE(0, A);
    MSTORE(1, B);
    MLOAD(A, 128);
    MLOAD(B, 192);
    __syncthreads();

    for (int k0 = 0; k0 < 16; k0 += 2) {
      MCOMPUTE(0);
      __syncthreads();
      if (k0 + 2 < 16) {
        MSTORE(0, A);
        if (k0 + 4 < 16) MLOAD(A, (k0 + 4) * 64);
      }
      MCOMPUTE(1);
      __syncthreads();
      if (k0 + 3 < 16) {
        MSTORE(1, B);
        if (k0 + 5 < 16) MLOAD(B, (k0 + 5) * 64);
      }
    }

    {
      floatx4 r0 = acc0A + acc0B, r1 = acc1A + acc1B;
#pragma unroll
      for (int r = 0; r < 4; ++r) {
        su.g.sR[0][g][ml][(lane >> 4) * 4 + r] = r0[r];
        su.g.sR[1][g][ml][(lane >> 4) * 4 + r] = r1[r];
      }
    }
    __syncthreads();

    int jj = tid & 15, bb = tid >> 4;
#pragma unroll
    for (int t2 = 0; t2 < 2; ++t2) {
      int jg = (t2 ? j0b : j0a) + jj;
      int b = b0 + bb;
      float ig = sigm(su.g.sR[t2][0][jj][bb] + bias[jg]);
      float fg = sigm(su.g.sR[t2][1][jj][bb] + bias[HID + jg]);
      float gg = tanhf(su.g.sR[t2][2][jj][bb] + bias[2 * HID + jg]);
      float og = sigm(su.g.sR[t2][3][jj][bb] + bias[3 * HID + jg]);
      float co = c[b * HID + jg];
      float cn = fg * co + ig * gg;
      float hv = og * tanhf(cn);
      c[b * HID + jg] = cn;
      out[((size_t)b * SEQL + t) * HID + jg] = hv;
      ushort hi = f2bf(hv);
      Dhi[(size_t)b * KDIM + IND + jg] = hi;
      Dlo[(size_t)b * KDIM + IND + jg] = f2bf(hv - bf2f(hi));
    }
  }
}

extern "C" void kernel_launch(void* const* d_in, const int* in_sizes, int n_in,
                              void* d_out, int out_size, void* d_ws, size_t ws_size,
                              hipStream_t stream) {
  (void)in_sizes; (void)n_in; (void)out_size; (void)ws_size;
  const float* x    = (const float*)d_in[0];
  const float* W_ih = (const float*)d_in[1];
  const float* W_hh = (const float*)d_in[2];
  const float* b_ih = (const float*)d_in[3];
  const float* b_hh = (const float*)d_in[4];
  const float* Wa   = (const float*)d_in[5];
  const float* ba   = (const float*)d_in[6];
  float* out = (float*)d_out;

  char* p = (char*)d_ws;
  auto carve = [&](size_t bytes) { char* r = p; p += (bytes + 255) & ~(size_t)255; return r; };
  unsigned* bar = (unsigned*)carve(1024);  // 16 group counters, 64B apart
  float*  c    = (float*)carve((size_t)BDIM * HID * 4);
  float*  bias = (float*)carve((size_t)4 * HID * 4);
  ushort* Whi  = (ushort*)carve((size_t)4 * HID * KDIM * 2);
  ushort* Wlo  = (ushort*)carve((size_t)4 * HID * KDIM * 2);
  ushort* A0hi = (ushort*)carve((size_t)BDIM * KDIM * 2);
  ushort* A0lo = (ushort*)carve((size_t)BDIM * KDIM * 2);
  ushort* A1hi = (ushort*)carve((size_t)BDIM * KDIM * 2);
  ushort* A1lo = (ushort*)carve((size_t)BDIM * KDIM * 2);
  _Float16* xh = (_Float16*)carve((size_t)BDIM * SEQL * IND * 2);

  hipMemsetAsync(bar, 0, 1024, stream);
  k_wconv<<<4 * HID, 256, 0, stream>>>(W_ih, W_hh, b_ih, b_hh, Whi, Wlo, bias);
  k_xconv<<<(BDIM * SEQL * IND) / (256 * 8), 256, 0, stream>>>(x, xh);
  k_init<<<BDIM, 256, 0, stream>>>(b_ih, b_hh, c, A0hi, A0lo);

  for (int t = 0; t < SEQL; ++t) {
    ushort* Rhi = (t & 1) ? A1hi : A0hi;
    ushort* Rlo = (t & 1) ? A1lo : A0lo;
    ushort* Dhi = (t & 1) ? A0hi : A1hi;
    ushort* Dlo = (t & 1) ? A0lo : A1lo;
    k_step<<<256, 256, 0, stream>>>(c, Wa, ba, xh, Whi, Wlo, bias,
                                    Rhi, Rlo, Dhi, Dlo, out, bar, t);
  }
}

// Round 14
// 4384.897 us; speedup vs baseline: 1.1803x; 1.1803x over previous
//
#include <hip/hip_runtime.h>
#include <stdint.h>

#define BDIM 256
#define SEQL 128
#define IND 512
#define HID 512
#define KDIM 1024 // IND + HID

typedef __bf16 bf16x8 __attribute__((ext_vector_type(8)));
typedef float floatx4 __attribute__((ext_vector_type(4)));
typedef _Float16 f16x8 __attribute__((ext_vector_type(8)));

__device__ __forceinline__ float sigm(float x) { return 1.0f / (1.0f + __expf(-x)); }

__device__ __forceinline__ ushort f2bf(float v) {
  uint32_t x = __builtin_bit_cast(uint32_t, v);
  x += 0x7fffu + ((x >> 16) & 1u);
  return (ushort)(x >> 16);
}
__device__ __forceinline__ float bf2f(ushort u) {
  return __builtin_bit_cast(float, ((uint32_t)u) << 16);
}

// ---- one-time: W -> bf16 hi/lo in [4H][IN|HID] row-major; combined bias ----
__global__ __launch_bounds__(256) void k_wconv(
    const float* __restrict__ W_ih, const float* __restrict__ W_hh,
    const float* __restrict__ b_ih, const float* __restrict__ b_hh,
    ushort* __restrict__ Whi, ushort* __restrict__ Wlo, float* __restrict__ bias) {
  int row = blockIdx.x;
  if (threadIdx.x == 0) bias[row] = b_ih[row] + b_hh[row];
  for (int k = threadIdx.x; k < KDIM; k += 256) {
    float w = (k < IND) ? W_ih[(size_t)row * IND + k] : W_hh[(size_t)row * HID + (k - IND)];
    ushort hi = f2bf(w);
    Whi[(size_t)row * KDIM + k] = hi;
    Wlo[(size_t)row * KDIM + k] = f2bf(w - bf2f(hi));
  }
}

// ---- one-time: x -> fp16 (R12-proven: halves the BW-bound xi stream) ----
__global__ __launch_bounds__(256) void k_xconv(const float* __restrict__ x,
                                               _Float16* __restrict__ xh) {
  size_t i = ((size_t)blockIdx.x * 256 + threadIdx.x) * 8;
  float4 v0 = *(const float4*)(x + i);
  float4 v1 = *(const float4*)(x + i + 4);
  f16x8 o;
  o[0] = (_Float16)v0.x; o[1] = (_Float16)v0.y; o[2] = (_Float16)v0.z; o[3] = (_Float16)v0.w;
  o[4] = (_Float16)v1.x; o[5] = (_Float16)v1.y; o[6] = (_Float16)v1.z; o[7] = (_Float16)v1.w;
  *(f16x8*)(xh + i) = o;
}

// ---- init: h0,c0 from the zero-input zero-state cell (gates = bias) ----
__global__ void k_init(const float* __restrict__ b_ih, const float* __restrict__ b_hh,
                       float* __restrict__ c, ushort* __restrict__ Ahi, ushort* __restrict__ Alo) {
  int b = blockIdx.x;
  for (int j = threadIdx.x; j < HID; j += blockDim.x) {
    float bi = b_ih[j] + b_hh[j];
    float bg = b_ih[2 * HID + j] + b_hh[2 * HID + j];
    float bo = b_ih[3 * HID + j] + b_hh[3 * HID + j];
    float c0 = sigm(bi) * tanhf(bg);
    float h0 = sigm(bo) * tanhf(c0);
    c[b * HID + j] = c0;
    ushort hi = f2bf(h0);
    Ahi[(size_t)b * KDIM + IND + j] = hi;
    Alo[(size_t)b * KDIM + IND + j] = f2bf(h0 - bf2f(hi));
  }
}

struct AttnS { float sc[HID]; float sl[SEQL]; float sxi[4][HID]; };  // ~10.5 KB
struct GemmS {
  ushort sA[2][2][16][72];   // [buf][hi/lo][batch][k] 9 KB
  ushort sW[2][2][64][72];   // [buf][hi/lo][row][k] 36 KB
  float  sR[4][16][16];      // gate exchange 4 KB (k2 only)
};
union SU { AttnS a; GemmS g; };  // ~49 KB -> 3 blocks/CU capacity

// GEMM staging/compute (R9-proven v3 body): split accA/accB chains
#define G3LOAD(R, KO) do { \
  R##a  = *(const uint4*)(gA + (KO)); \
  R##w0 = *(const uint4*)(gWhi + (KO));      R##w1 = *(const uint4*)(gWhi + (KO) + 8);  \
  R##w2 = *(const uint4*)(gWlo + (KO));      R##w3 = *(const uint4*)(gWlo + (KO) + 8);  } while (0)
#define G3STORE(BUF, R) do { \
  *(uint4*)&su.g.sA[BUF][sthalf][ar][ac] = R##a; \
  *(uint4*)&su.g.sW[BUF][0][wr][wc] = R##w0;  *(uint4*)&su.g.sW[BUF][0][wr][wc + 8] = R##w1; \
  *(uint4*)&su.g.sW[BUF][1][wr][wc] = R##w2;  *(uint4*)&su.g.sW[BUF][1][wr][wc + 8] = R##w3; } while (0)
#define G3COMPUTE(BUF) do { \
  _Pragma("unroll") for (int ks = 0; ks < 2; ++ks) { \
    int kb = ks * 32 + koff; \
    bf16x8 ah = *(const bf16x8*)(&su.g.sA[BUF][0][ml][kb]); \
    bf16x8 al = *(const bf16x8*)(&su.g.sA[BUF][1][ml][kb]); \
    bf16x8 wh = *(const bf16x8*)(&su.g.sW[BUF][0][g * 16 + ml][kb]); \
    bf16x8 wl = *(const bf16x8*)(&su.g.sW[BUF][1][g * 16 + ml][kb]); \
    accA = __builtin_amdgcn_mfma_f32_16x16x32_bf16(ah, wh, accA, 0, 0, 0); \
    accB = __builtin_amdgcn_mfma_f32_16x16x32_bf16(ah, wl, accB, 0, 0, 0); \
    accB = __builtin_amdgcn_mfma_f32_16x16x32_bf16(al, wh, accB, 0, 0, 0); } } while (0)
// 8-chunk pipelined K-loop (prologue stages 0,1; loads 2,3 in flight)
#define G3LOOP(NCH) \
  G3LOAD(A, 0); G3LOAD(B, 64); \
  G3STORE(0, A); G3STORE(1, B); \
  G3LOAD(A, 128); G3LOAD(B, 192); \
  __syncthreads(); \
  for (int k0 = 0; k0 < (NCH); k0 += 2) { \
    G3COMPUTE(0); \
    __syncthreads(); \
    if (k0 + 2 < (NCH)) { G3STORE(0, A); if (k0 + 4 < (NCH)) G3LOAD(A, (k0 + 4) * 64); } \
    G3COMPUTE(1); \
    __syncthreads(); \
    if (k0 + 3 < (NCH)) { G3STORE(1, B); if (k0 + 5 < (NCH)) G3LOAD(B, (k0 + 5) * 64); } \
  }

// ---- k1: 768 blocks. Blocks 0..255: attn for batch bid (R12 body).
// Blocks 256..767: gates_h -- the h-half (K=512..1023) of the gates GEMM,
// which depends ONLY on step t-1 state, so it runs CONCURRENTLY with attn.
// 3 blocks/CU mixed: gates_h's MFMA waves fill attn's latency stalls (the
// R13 counters showed 45 of 48.6 us/step is stall at 1 block/CU).
__global__ __launch_bounds__(256) void k1_attn_gatesH(
    const float* __restrict__ c, const float* __restrict__ Wa,
    const float* __restrict__ ba, const _Float16* __restrict__ xh,
    const ushort* __restrict__ Whi, const ushort* __restrict__ Wlo,
    ushort* __restrict__ Rhi, ushort* __restrict__ Rlo,
    float* __restrict__ P) {
  __shared__ __align__(16) SU su;
  int blk = blockIdx.x, tid = threadIdx.x;
  int lane = tid & 63, wave = tid >> 6;

  if (blk < 256) {
    // ================= ATTN (R12-proven body) =================
    int b = blk;
    su.a.sc[tid] = c[b * HID + tid];
    su.a.sc[tid + 256] = c[b * HID + tid + 256];
    __syncthreads();
    float4 c0 = *(const float4*)(&su.a.sc[lane * 4]);
    float4 c1 = *(const float4*)(&su.a.sc[lane * 4 + 256]);
#pragma unroll 4
    for (int si = 0; si < 32; ++si) {
      int s = wave * 32 + si;
      const float4* wr4 = (const float4*)(Wa + (size_t)s * HID);
      float4 w0 = wr4[lane];
      float4 w1 = wr4[lane + 64];
      float acc = c0.x * w0.x + c0.y * w0.y + c0.z * w0.z + c0.w * w0.w
                + c1.x * w1.x + c1.y * w1.y + c1.z * w1.z + c1.w * w1.w;
#pragma unroll
      for (int off = 32; off > 0; off >>= 1) acc += __shfl_down(acc, off);
      if (lane == 0) su.a.sl[s] = acc + ba[s];
    }
    __syncthreads();
    if (tid < 64) {
      float v0 = su.a.sl[tid], v1 = su.a.sl[tid + 64];
      float m = fmaxf(v0, v1);
#pragma unroll
      for (int off = 32; off > 0; off >>= 1) m = fmaxf(m, __shfl_xor(m, off));
      float e0 = __expf(v0 - m), e1 = __expf(v1 - m);
      float s2 = e0 + e1;
#pragma unroll
      for (int off = 32; off > 0; off >>= 1) s2 += __shfl_xor(s2, off);
      float inv = 1.f / s2;
      su.a.sl[tid] = e0 * inv; su.a.sl[tid + 64] = e1 * inv;
    }
    __syncthreads();
    int cix = tid & 63, qp = tid >> 6;
    const _Float16* xrow = xh + (size_t)b * SEQL * IND + (size_t)qp * 32 * IND + 8 * cix;
    float a0 = 0.f, a1 = 0.f, a2 = 0.f, a3 = 0.f, a4 = 0.f, a5 = 0.f, a6 = 0.f, a7 = 0.f;
#pragma unroll 8
    for (int s = 0; s < 32; ++s) {
      float w = su.a.sl[qp * 32 + s];
      f16x8 v = *(const f16x8*)(xrow + (size_t)s * IND);
      a0 += w * (float)v[0]; a1 += w * (float)v[1];
      a2 += w * (float)v[2]; a3 += w * (float)v[3];
      a4 += w * (float)v[4]; a5 += w * (float)v[5];
      a6 += w * (float)v[6]; a7 += w * (float)v[7];
    }
    *(float4*)(&su.a.sxi[qp][8 * cix])     = (float4){a0, a1, a2, a3};
    *(float4*)(&su.a.sxi[qp][8 * cix + 4]) = (float4){a4, a5, a6, a7};
    __syncthreads();
    float rx = su.a.sxi[0][2 * tid] + su.a.sxi[1][2 * tid] + su.a.sxi[2][2 * tid] + su.a.sxi[3][2 * tid];
    float ry = su.a.sxi[0][2 * tid + 1] + su.a.sxi[1][2 * tid + 1] + su.a.sxi[2][2 * tid + 1] + su.a.sxi[3][2 * tid + 1];
    ushort hx = f2bf(rx), hy = f2bf(ry);
    uint hp = (uint)hx | ((uint)hy << 16);
    uint lp = (uint)f2bf(rx - bf2f(hx)) | ((uint)f2bf(ry - bf2f(hy)) << 16);
    *(uint*)(Rhi + (size_t)b * KDIM + 2 * tid) = hp;  // xi region: cols 0..511
    *(uint*)(Rlo + (size_t)b * KDIM + 2 * tid) = lp;
  } else {
    // ================= gates_h: K=[512,1024), write P partials ============
    int g2 = blk - 256;                       // (256+g2)%8 == g2%8 -> R9 XCD map
    int lb = (g2 & 7) * 64 + (g2 >> 3);
    int j0 = (lb >> 4) * 16;
    int b0 = (lb & 15) * 16;
    int sthalf = tid >> 7;
    int ar = (tid & 127) >> 3, ac = (tid & 7) * 8;
    const ushort* gA = (sthalf ? Rlo : Rhi) + (size_t)(b0 + ar) * KDIM + IND + ac;  // h region
    int wr = tid >> 2, wc = (tid & 3) * 16;
    int wrow = (wr >> 4) * HID + j0 + (wr & 15);
    const ushort* gWhi = Whi + (size_t)wrow * KDIM + IND + wc;
    const ushort* gWlo = Wlo + (size_t)wrow * KDIM + IND + wc;

    floatx4 accA = {0.f, 0.f, 0.f, 0.f}, accB = {0.f, 0.f, 0.f, 0.f};
    int g = tid >> 6, ml = lane & 15, koff = (lane >> 4) * 8;
    uint4 Aa, Aw0, Aw1, Aw2, Aw3, Ba, Bw0, Bw1, Bw2, Bw3;
    G3LOOP(8)

    // direct P write: tile (g, jt=j0/16, bt=b0/16), [j][b] dense, b fastest.
    floatx4 acc = accA + accB;
    size_t pbase = (((size_t)g * 32 + (j0 >> 4)) * 16 + (b0 >> 4)) * 256;
    *(float4*)(P + pbase + ml * 16 + (lane >> 4) * 4) = *(float4*)&acc;
  }
}

// ---- k2: gates_x -- K=[0,512) (xi) + P + fused cell update. 512 blocks,
// 2/CU (R9-proven TLP), R9 body with half the k-loop.
__global__ __launch_bounds__(256) void k2_gatesX(
    const ushort* __restrict__ Whi, const ushort* __restrict__ Wlo,
    const float* __restrict__ bias, const float* __restrict__ P,
    const ushort* __restrict__ Rhi, const ushort* __restrict__ Rlo,
    float* __restrict__ c, float* __restrict__ out,
    ushort* __restrict__ Dhi, ushort* __restrict__ Dlo, int tstep) {
  __shared__ __align__(16) SU su;
  int bid = blockIdx.x, tid = threadIdx.x;
  int lane = tid & 63;
  int lb = (bid & 7) * 64 + (bid >> 3);
  int j0 = (lb >> 4) * 16;
  int b0 = (lb & 15) * 16;
  int sthalf = tid >> 7;
  int ar = (tid & 127) >> 3, ac = (tid & 7) * 8;
  const ushort* gA = (sthalf ? Rlo : Rhi) + (size_t)(b0 + ar) * KDIM + ac;  // xi region
  int wr = tid >> 2, wc = (tid & 3) * 16;
  int wrow = (wr >> 4) * HID + j0 + (wr & 15);
  const ushort* gWhi = Whi + (size_t)wrow * KDIM + wc;
  const ushort* gWlo = Wlo + (size_t)wrow * KDIM + wc;

  floatx4 accA = {0.f, 0.f, 0.f, 0.f}, accB = {0.f, 0.f, 0.f, 0.f};
  int g = tid >> 6, ml = lane & 15, koff = (lane >> 4) * 8;
  uint4 Aa, Aw0, Aw1, Aw2, Aw3, Ba, Bw0, Bw1, Bw2, Bw3;
  G3LOOP(8)

  {
    floatx4 acc = accA + accB;
#pragma unroll
    for (int r = 0; r < 4; ++r) su.g.sR[g][ml][(lane >> 4) * 4 + r] = acc[r];
  }
  __syncthreads();

  {
    int jj = tid & 15, bb = tid >> 4;
    int jg = j0 + jj;
    int b = b0 + bb;
    size_t pb = (((size_t)(j0 >> 4)) * 16 + (b0 >> 4)) * 256 + jj * 16 + bb;
    const size_t gstr = (size_t)32 * 16 * 256;
    float ig = sigm(su.g.sR[0][jj][bb] + P[pb]            + bias[jg]);
    float fg = sigm(su.g.sR[1][jj][bb] + P[pb + gstr]     + bias[HID + jg]);
    float gg = tanhf(su.g.sR[2][jj][bb] + P[pb + 2 * gstr] + bias[2 * HID + jg]);
    float og = sigm(su.g.sR[3][jj][bb] + P[pb + 3 * gstr] + bias[3 * HID + jg]);
    float co = c[b * HID + jg];
    float cn = fg * co + ig * gg;
    float hv = og * tanhf(cn);
    c[b * HID + jg] = cn;
    out[((size_t)b * SEQL + tstep) * HID + jg] = hv;
    ushort hi = f2bf(hv);
    Dhi[(size_t)b * KDIM + IND + jg] = hi;
    Dlo[(size_t)b * KDIM + IND + jg] = f2bf(hv - bf2f(hi));
  }
}

extern "C" void kernel_launch(void* const* d_in, const int* in_sizes, int n_in,
                              void* d_out, int out_size, void* d_ws, size_t ws_size,
                              hipStream_t stream) {
  (void)in_sizes; (void)n_in; (void)out_size; (void)ws_size;
  const float* x    = (const float*)d_in[0];
  const float* W_ih = (const float*)d_in[1];
  const float* W_hh = (const float*)d_in[2];
  const float* b_ih = (const float*)d_in[3];
  const float* b_hh = (const float*)d_in[4];
  const float* Wa   = (const float*)d_in[5];
  const float* ba   = (const float*)d_in[6];
  float* out = (float*)d_out;

  // ws footprint: ~46 MiB
  char* p = (char*)d_ws;
  auto carve = [&](size_t bytes) { char* r = p; p += (bytes + 255) & ~(size_t)255; return r; };
  float*  c    = (float*)carve((size_t)BDIM * HID * 4);
  float*  bias = (float*)carve((size_t)4 * HID * 4);
  ushort* Whi  = (ushort*)carve((size_t)4 * HID * KDIM * 2);
  ushort* Wlo  = (ushort*)carve((size_t)4 * HID * KDIM * 2);
  ushort* A0hi = (ushort*)carve((size_t)BDIM * KDIM * 2);
  ushort* A0lo = (ushort*)carve((size_t)BDIM * KDIM * 2);
  ushort* A1hi = (ushort*)carve((size_t)BDIM * KDIM * 2);
  ushort* A1lo = (ushort*)carve((size_t)BDIM * KDIM * 2);
  _Float16* xh = (_Float16*)carve((size_t)BDIM * SEQL * IND * 2);
  float*  P    = (float*)carve((size_t)4 * HID * BDIM * 4);  // 2 MB partials

  k_wconv<<<4 * HID, 256, 0, stream>>>(W_ih, W_hh, b_ih, b_hh, Whi, Wlo, bias);
  k_xconv<<<(BDIM * SEQL * IND) / (256 * 8), 256, 0, stream>>>(x, xh);
  k_init<<<BDIM, 256, 0, stream>>>(b_ih, b_hh, c, A0hi, A0lo);

  for (int t = 0; t < SEQL; ++t) {
    ushort* Rhi = (t & 1) ? A1hi : A0hi;
    ushort* Rlo = (t & 1) ? A1lo : A0lo;
    ushort* Dhi = (t & 1) ? A0hi : A1hi;
    ushort* Dlo = (t & 1) ? A0lo : A1lo;
    k1_attn_gatesH<<<768, 256, 0, stream>>>(c, Wa, ba, xh, Whi, Wlo, Rhi, Rlo, P);
    k2_gatesX<<<512, 256, 0, stream>>>(Whi, Wlo, bias, P, Rhi, Rlo, c, out, Dhi, Dlo, t);
  }
}